// Round 1
// baseline (320.599 us; speedup 1.0000x reference)
//
#include <hip/hip_runtime.h>
#include <hip/hip_bf16.h>

typedef unsigned short u16;
typedef __bf16 bf16x8 __attribute__((ext_vector_type(8)));
typedef float f32x4 __attribute__((ext_vector_type(4)));

#define AS1(p) ((const __attribute__((address_space(1))) void*)(p))
#define AS3(p) ((__attribute__((address_space(3))) void*)(p))

#define BATCH 128
#define TOK   256
#define NH    16
#define HD    32
#define CDIM  512
#define QKVC  1536
#define SCALE 0.17677669529663687f

__device__ __forceinline__ u16 f2b(float f) {
  unsigned u = __float_as_uint(f);
  unsigned r = (u + 0x7fffu + ((u >> 16) & 1u)) >> 16;
  return (u16)r;
}
__device__ __forceinline__ float b2f(u16 h) {
  return __uint_as_float(((unsigned)h) << 16);
}

// ---------------- fp32 -> bf16 conversion ----------------
__global__ __launch_bounds__(256) void cvt_bf16_kernel(const float* __restrict__ in,
                                                       u16* __restrict__ out, int n) {
  int i = (blockIdx.x * 256 + threadIdx.x) * 8;
  if (i >= n) return;
  float4 a = *(const float4*)(in + i);
  float4 b = *(const float4*)(in + i + 4);
  u16 h[8];
  h[0] = f2b(a.x); h[1] = f2b(a.y); h[2] = f2b(a.z); h[3] = f2b(a.w);
  h[4] = f2b(b.x); h[5] = f2b(b.y); h[6] = f2b(b.z); h[7] = f2b(b.w);
  *(uint4*)(out + i) = *(const uint4*)h;
}

// ---------------- bias table: bias[h][n][m] = rpb[relidx(n,m)*16+h] ----------------
__global__ __launch_bounds__(256) void build_bias_kernel(const float* __restrict__ rpb,
                                                         float* __restrict__ biasT) {
  int i = blockIdx.x * 256 + threadIdx.x;   // 16*256*256
  int m = i & 255, n = (i >> 8) & 255, h = i >> 16;
  int rn = n >> 4, cn = n & 15, rm = m >> 4, cm = m & 15;
  int idx = (rn - rm + 15) * 31 + (cn - cm + 15);
  biasT[i] = rpb[idx * 16 + h];
}

// ---------------- modulation table mod[n][m] ----------------
__global__ __launch_bounds__(256) void build_mod_kernel(float* __restrict__ mod) {
  int i = blockIdx.x * 256 + threadIdx.x;   // 256*256
  int m = i & 255, n = i >> 8;
  int dr = (n >> 4) - (m >> 4), dc = (n & 15) - (m & 15);
  int d2 = dr * dr + dc * dc;
  float val = 0.0f;
  if (d2 <= 229) {   // exact integer form of (m >= bound); bound at d2==229
    const float fc = 6.2831853071795864f / (60.0f * 1.4142135623730951f);
    float d = sqrtf((float)d2);
    val = expf(cosf(fc * d)) * 0.5f;
  }
  mod[i] = val;
}

// ---------------- bf16 GEMM: out = A[M,K] @ Bt[N,K]^T (+bias epilogue) ----------------
// MODE 0: qkv epilogue (bf16 out [M][1536], scale cols<512)
// MODE 1: proj epilogue (f32 out [M][512])
template<int NDIM, int MODE>
__global__ __launch_bounds__(256) void gemm_bt(const u16* __restrict__ A,
                                               const u16* __restrict__ Bt,
                                               const float* __restrict__ bvec,
                                               void* __restrict__ outp) {
  constexpr int K = 512;
  __shared__ __align__(16) u16 As[128 * 64];
  __shared__ __align__(16) u16 Bs[128 * 64];
  const int tid = threadIdx.x, lane = tid & 63, w = tid >> 6;
  const int wr = w >> 1, wc = w & 1, lr = lane & 15, lg = lane >> 4;
  const int bm = blockIdx.x, bn = blockIdx.y;
  const u16* Ag = A + (size_t)bm * 128 * K;
  const u16* Bg = Bt + (size_t)bn * 128 * K;
  f32x4 acc[4][4];
#pragma unroll
  for (int m = 0; m < 4; ++m)
#pragma unroll
    for (int n = 0; n < 4; ++n) acc[m][n] = (f32x4){0.f, 0.f, 0.f, 0.f};

  for (int k0 = 0; k0 < K; k0 += 64) {
#pragma unroll
    for (int it = 0; it < 4; ++it) {
      int chunk = it * 256 + w * 64 + lane;   // 16B chunk id, [128 rows][8 chunks]
      int r = chunk >> 3, kc = chunk & 7;
      __builtin_amdgcn_global_load_lds(AS1(Ag + (size_t)r * K + k0 + kc * 8),
                                       AS3(As + (it * 256 + w * 64) * 8), 16, 0, 0);
      __builtin_amdgcn_global_load_lds(AS1(Bg + (size_t)r * K + k0 + kc * 8),
                                       AS3(Bs + (it * 256 + w * 64) * 8), 16, 0, 0);
    }
    __syncthreads();
#pragma unroll
    for (int kk = 0; kk < 2; ++kk) {
      bf16x8 a[4], b[4];
#pragma unroll
      for (int m = 0; m < 4; ++m)
        a[m] = *(const bf16x8*)&As[(wr * 64 + m * 16 + lr) * 64 + kk * 32 + lg * 8];
#pragma unroll
      for (int n = 0; n < 4; ++n)
        b[n] = *(const bf16x8*)&Bs[(wc * 64 + n * 16 + lr) * 64 + kk * 32 + lg * 8];
#pragma unroll
      for (int m = 0; m < 4; ++m)
#pragma unroll
        for (int n = 0; n < 4; ++n)
          acc[m][n] = __builtin_amdgcn_mfma_f32_16x16x32_bf16(a[m], b[n], acc[m][n], 0, 0, 0);
    }
    __syncthreads();
  }
#pragma unroll
  for (int m = 0; m < 4; ++m)
#pragma unroll
    for (int n = 0; n < 4; ++n)
#pragma unroll
      for (int r = 0; r < 4; ++r) {
        int row = bm * 128 + wr * 64 + m * 16 + lg * 4 + r;
        int col = bn * 128 + wc * 64 + n * 16 + lr;
        float v = acc[m][n][r] + bvec[col];
        if (MODE == 0) {
          if (col < 512) v *= SCALE;
          ((u16*)outp)[(size_t)row * NDIM + col] = f2b(v);
        } else {
          ((float*)outp)[(size_t)row * NDIM + col] = v;
        }
      }
}

// ---------------- fused attention per (b, h, qblock of 64 rows) ----------------
__global__ __launch_bounds__(256) void attn_kernel(const u16* __restrict__ qkv,   // [32768][1536]
                                                   const float* __restrict__ biasT, // [16][256][256]
                                                   const float* __restrict__ modt,  // [256][256]
                                                   u16* __restrict__ attnout) {     // [32768][512]
  __shared__ __align__(16) u16 Ks[256 * 32];
  __shared__ __align__(16) u16 Vt[32 * 256];
  __shared__ __align__(16) u16 Ps[4 * 16 * 256];
  const int blk = blockIdx.x;          // 128*16*4
  const int b = blk >> 6;
  const int h = (blk >> 2) & 15;
  const int qb = blk & 3;
  const int tid = threadIdx.x, lane = tid & 63, w = tid >> 6;
  const int lr = lane & 15, lg = lane >> 4;
  const int n0 = qb * 64 + w * 16;     // this wave's 16 query rows

  // stage K [256][32] bf16 directly to LDS
  const u16* kbase = qkv + (size_t)b * TOK * QKVC + 512 + h * 32;
#pragma unroll
  for (int it = 0; it < 4; ++it) {
    int chunk = (it * 4 + w) * 64 + lane;  // [256 rows][4 segs of 8 bf16]
    int r = chunk >> 2, seg = chunk & 3;
    __builtin_amdgcn_global_load_lds(AS1(kbase + (size_t)r * QKVC + seg * 8),
                                     AS3(Ks + (it * 4 + w) * 512), 16, 0, 0);
  }
  // stage V transposed: Vt[d][m]
  {
    const u16* vrow = qkv + (size_t)(b * TOK + tid) * QKVC + 1024 + h * 32;
    u16 tmp[32];
    *(uint4*)&tmp[0]  = *(const uint4*)(vrow + 0);
    *(uint4*)&tmp[8]  = *(const uint4*)(vrow + 8);
    *(uint4*)&tmp[16] = *(const uint4*)(vrow + 16);
    *(uint4*)&tmp[24] = *(const uint4*)(vrow + 24);
#pragma unroll
    for (int d = 0; d < 32; ++d) Vt[d * 256 + tid] = tmp[d];
  }
  __syncthreads();

  // Q fragment straight from global (pre-scaled at qkv epilogue)
  const u16* qrow = qkv + (size_t)(b * TOK + n0 + lr) * QKVC + h * 32 + lg * 8;
  bf16x8 qf = *(const bf16x8*)qrow;

  // S = Q @ K^T : 16 tiles of 16x16 per wave
  f32x4 s[16];
#pragma unroll
  for (int t = 0; t < 16; ++t) {
    bf16x8 kf = *(const bf16x8*)&Ks[(t * 16 + lr) * 32 + lg * 8];
    s[t] = __builtin_amdgcn_mfma_f32_16x16x32_bf16(qf, kf, (f32x4){0.f, 0.f, 0.f, 0.f}, 0, 0, 0);
  }

  // + bias
  const float* brow = biasT + ((size_t)h * 256 + n0 + lg * 4) * 256;
#pragma unroll
  for (int t = 0; t < 16; ++t)
#pragma unroll
    for (int r = 0; r < 4; ++r) s[t][r] += brow[r * 256 + t * 16 + lr];

  // softmax over m (cols): reduce over t in-lane, then over 16 lanes (lr)
  float mx[4];
#pragma unroll
  for (int r = 0; r < 4; ++r) {
    float m = s[0][r];
#pragma unroll
    for (int t = 1; t < 16; ++t) m = fmaxf(m, s[t][r]);
#pragma unroll
    for (int off = 1; off < 16; off <<= 1) m = fmaxf(m, __shfl_xor(m, off, 64));
    mx[r] = m;
  }
  float sum[4] = {0.f, 0.f, 0.f, 0.f};
#pragma unroll
  for (int t = 0; t < 16; ++t)
#pragma unroll
    for (int r = 0; r < 4; ++r) {
      s[t][r] = __expf(s[t][r] - mx[r]);
      sum[r] += s[t][r];
    }
#pragma unroll
  for (int r = 0; r < 4; ++r) {
#pragma unroll
    for (int off = 1; off < 16; off <<= 1) sum[r] += __shfl_xor(sum[r], off, 64);
    sum[r] = 1.0f / sum[r];
  }

  // attn = softmax * mod, write P tile (bf16) for PV mfma
#pragma unroll
  for (int t = 0; t < 16; ++t)
#pragma unroll
    for (int r = 0; r < 4; ++r) {
      float av = s[t][r] * sum[r] * modt[(size_t)(n0 + lg * 4 + r) * 256 + t * 16 + lr];
      Ps[(w * 16 + lg * 4 + r) * 256 + t * 16 + lr] = f2b(av);
    }
  __syncthreads();

  // O = P @ V : [16 rows][32 cols] per wave, K=256
  f32x4 o[2];
  o[0] = (f32x4){0.f, 0.f, 0.f, 0.f};
  o[1] = (f32x4){0.f, 0.f, 0.f, 0.f};
#pragma unroll
  for (int kk = 0; kk < 8; ++kk) {
    bf16x8 pa = *(const bf16x8*)&Ps[(w * 16 + lr) * 256 + kk * 32 + lg * 8];
#pragma unroll
    for (int t2 = 0; t2 < 2; ++t2) {
      bf16x8 vb = *(const bf16x8*)&Vt[(t2 * 16 + lr) * 256 + kk * 32 + lg * 8];
      o[t2] = __builtin_amdgcn_mfma_f32_16x16x32_bf16(pa, vb, o[t2], 0, 0, 0);
    }
  }
#pragma unroll
  for (int t2 = 0; t2 < 2; ++t2)
#pragma unroll
    for (int r = 0; r < 4; ++r)
      attnout[(size_t)(b * TOK + n0 + lg * 4 + r) * CDIM + h * 32 + t2 * 16 + lr] = f2b(o[t2][r]);
}

// ---------------- launch ----------------
extern "C" void kernel_launch(void* const* d_in, const int* in_sizes, int n_in,
                              void* d_out, int out_size, void* d_ws, size_t ws_size,
                              hipStream_t stream) {
  const float* x      = (const float*)d_in[0];
  const float* qkv_w  = (const float*)d_in[1];
  const float* qkv_b  = (const float*)d_in[2];
  const float* proj_w = (const float*)d_in[3];
  const float* proj_b = (const float*)d_in[4];
  const float* rpb    = (const float*)d_in[5];

  char* ws = (char*)d_ws;
  u16*   xb     = (u16*)(ws);                         // 32768*512*2   = 33,554,432
  u16*   qkvwb  = (u16*)(ws + 33554432);              // 1536*512*2    = 1,572,864
  u16*   projwb = (u16*)(ws + 35127296);              // 512*512*2     = 524,288
  u16*   qkvbuf = (u16*)(ws + 35651584);              // 32768*1536*2  = 100,663,296
  u16*   attnb  = (u16*)(ws + 136314880);             // 32768*512*2   = 33,554,432
  float* biasT  = (float*)(ws + 169869312);           // 16*256*256*4  = 4,194,304
  float* modt   = (float*)(ws + 174063616);           // 256*256*4     = 262,144

  cvt_bf16_kernel<<<8192, 256, 0, stream>>>(x, xb, 32768 * 512);
  cvt_bf16_kernel<<<384, 256, 0, stream>>>(qkv_w, qkvwb, 1536 * 512);
  cvt_bf16_kernel<<<128, 256, 0, stream>>>(proj_w, projwb, 512 * 512);
  build_bias_kernel<<<4096, 256, 0, stream>>>(rpb, biasT);
  build_mod_kernel<<<256, 256, 0, stream>>>(modt);

  gemm_bt<QKVC, 0><<<dim3(256, 12), 256, 0, stream>>>(xb, qkvwb, qkv_b, qkvbuf);
  attn_kernel<<<128 * 16 * 4, 256, 0, stream>>>(qkvbuf, biasT, modt, attnb);
  gemm_bt<CDIM, 1><<<dim3(256, 4), 256, 0, stream>>>(attnb, projwb, proj_b, d_out);
}